// Round 7
// baseline (158.794 us; speedup 1.0000x reference)
//
#include <hip/hip_runtime.h>

typedef unsigned short ushort_t;
typedef ushort_t u16x8 __attribute__((ext_vector_type(8)));
typedef __bf16 bf16x8 __attribute__((ext_vector_type(8)));
typedef float f32x4 __attribute__((ext_vector_type(4)));

#define DET 736
#define HALF 368           // real half-size (even or odd samples)
#define HK 384             // padded K and padded output-half columns
#define NTT 12             // K-tiles of 32 (384/32)
#define CPB2 (NTT * 64)    // 768 frag-chunks per 16-row (or 16-col) block
#define NRB 1152           // M/16 row-blocks (M = 18432)

// ---------------------------------------------------------------------------
// PARITY SPLIT.  h[d]=0 for even d!=0, so with g[k]=0.05*cos((k-367.5)e-3):
//   OUT[m][2i]   = sum_j x[m][2j+1] g[2j+1] h[2(j-i)+1]  +  h0 g[2i]   x[m][2i]
//   OUT[m][2i+1] = sum_j x[m][2j]   g[2j]   h[2(j-i)-1]  +  h0 g[2i+1] x[m][2i+1]
// Two M x 384 x 384 GEMMs (half FLOPs, half A-bytes of round 6); diagonal term
// added in epilogue from raw fp32 sinogram.  g folded into B (row-index dep).
// Fragment-major layouts identical to round 6 (chunk=(blk16,t,lane), lane's 8
// elems contiguous): A lane&15=row, B lane&15=out-col, lane>>4 = k-subchunk.
// ---------------------------------------------------------------------------

// Ae = odd-k samples (feeds even outputs), Ao = even-k samples (feeds odd).
__global__ void prep_af(const float* __restrict__ sino,
                        ushort_t* __restrict__ Ae, ushort_t* __restrict__ Ao) {
    int c = blockIdx.x * blockDim.x + threadIdx.x;   // exact grid: NRB*CPB2
    int rblk = c / CPB2;
    int rem  = c - rblk * CPB2;
    int t = rem >> 6, lane = rem & 63;
    int rr = lane & 15, quad = lane >> 4;
    int j0 = t * 32 + quad * 8;        // first of 8 half-K indices (mult of 8)
    u16x8 ve, vo;
    if (j0 < HALF) {                   // j0<=360 -> all 8 real
        const float* g = sino + (size_t)(rblk * 16 + rr) * DET + 2 * j0;
        float w[16];
        *(f32x4*)(w)      = *(const f32x4*)(g);
        *(f32x4*)(w + 4)  = *(const f32x4*)(g + 4);
        *(f32x4*)(w + 8)  = *(const f32x4*)(g + 8);
        *(f32x4*)(w + 12) = *(const f32x4*)(g + 12);
#pragma unroll
        for (int e = 0; e < 8; ++e) {
            vo[e] = __builtin_bit_cast(ushort_t, (__bf16)w[2 * e]);      // k even
            ve[e] = __builtin_bit_cast(ushort_t, (__bf16)w[2 * e + 1]);  // k odd
        }
    } else {
#pragma unroll
        for (int e = 0; e < 8; ++e) { ve[e] = 0; vo[e] = 0; }
    }
    *(u16x8*)(Ae + (size_t)c * 8) = ve;
    *(u16x8*)(Ao + (size_t)c * 8) = vo;
}

// Be[i][j] = g(2j+1) h[2(j-i)+1]  (even outputs);  Bo[i][j] = g(2j) h[2(j-i)-1].
// Frag-major: chunk (cb,t,lane): i = cb*16+(lane&15), j = t*32+(lane>>4)*8+e.
__global__ void prep_bf(const float* __restrict__ filt,
                        ushort_t* __restrict__ Be, ushort_t* __restrict__ Bo) {
    int c = blockIdx.x * blockDim.x + threadIdx.x;   // exact: 24*CPB2 = 18432
    int cb  = c / CPB2;
    int rem = c - cb * CPB2;
    int t = rem >> 6, lane = rem & 63;
    int i = cb * 16 + (lane & 15);
    int quad = lane >> 4;
    u16x8 ve, vo;
#pragma unroll
    for (int e = 0; e < 8; ++e) {
        int j = t * 32 + quad * 8 + e;
        bool real = (j < HALF) && (i < HALF);
        // clamped (always in-bounds) filter indices; result masked by `real`
        int de = 2 * (j - i) + 1 + 735;                       // [-30,1502] raw
        int do_ = de - 2;
        de  = de  < 0 ? 0 : (de  > 1470 ? 1470 : de);
        do_ = do_ < 0 ? 0 : (do_ > 1470 ? 1470 : do_);
        float ge = 0.05f * cosf(((float)(2 * j + 1) - 367.5f) * 0.001f);
        float go = 0.05f * cosf(((float)(2 * j)     - 367.5f) * 0.001f);
        float fe = filt[de] * ge;
        float fo = filt[do_] * go;
        ve[e] = real ? __builtin_bit_cast(ushort_t, (__bf16)fe) : (ushort_t)0;
        vo[e] = real ? __builtin_bit_cast(ushort_t, (__bf16)fo) : (ushort_t)0;
    }
    *(u16x8*)(Be + (size_t)c * 8) = ve;
    *(u16x8*)(Bo + (size_t)c * 8) = vo;
}

// One parity-GEMM per blockIdx.z.  Block = 16 waves (8M x 2N) = 512 rows x 128
// half-cols; B strip (8 col-blocks x K=384 = 96 KB) staged to LDS once (single
// barrier); A frags global->reg lane-contiguous with 1-deep prefetch; K-loop
// has zero barriers.  A L3 re-read: 3 strips x 2 parities x 14.2 MB = 85 MB.
__global__ __launch_bounds__(1024, 4) void gemm_half(
    const ushort_t* __restrict__ Ae, const ushort_t* __restrict__ Ao,
    const ushort_t* __restrict__ Be, const ushort_t* __restrict__ Bo,
    const float* __restrict__ sino, const float* __restrict__ filt,
    float* __restrict__ C)
{
    __shared__ ushort_t Bs[8 * CPB2 * 8];   // 49152 elems = 96 KB

    const int p    = blockIdx.z;            // 0: even outputs, 1: odd
    const ushort_t* Af = p ? Ao : Ae;
    const ushort_t* Bf = p ? Bo : Be;

    const int tid  = threadIdx.x;
    const int lane = tid & 63;
    const int wid  = tid >> 6;              // 0..15
    const int wm   = wid >> 1;              // 0..7
    const int wn   = wid & 1;               // 0..1
    const int quad = lane >> 4;
    const int l16  = lane & 15;

    // stage B strip once (frag-linear, coalesced)
    const int cbg0 = blockIdx.y * 8;        // global col-block base of strip
    {
        const ushort_t* bsrc = Bf + (size_t)cbg0 * CPB2 * 8;
        for (int c = tid; c < 8 * CPB2; c += 1024)
            *(u16x8*)(Bs + c * 8) = *(const u16x8*)(bsrc + (size_t)c * 8);
    }
    __syncthreads();   // the only barrier

    const int rblk0 = blockIdx.x * 32 + wm * 4;   // 4 row-blocks per wave

    f32x4 acc[4][4];
#pragma unroll
    for (int i = 0; i < 4; ++i)
#pragma unroll
        for (int j = 0; j < 4; ++j)
            acc[i][j] = (f32x4){0.f, 0.f, 0.f, 0.f};

    const ushort_t* pA[4];
#pragma unroll
    for (int mi = 0; mi < 4; ++mi)
        pA[mi] = Af + ((size_t)(rblk0 + mi) * CPB2 + lane) * 8;
    const ushort_t* pB[4];
#pragma unroll
    for (int ni = 0; ni < 4; ++ni)
        pB[ni] = Bs + ((wn * 4 + ni) * CPB2 + lane) * 8;

    u16x8 acur[4];
#pragma unroll
    for (int mi = 0; mi < 4; ++mi)
        acur[mi] = *(const u16x8*)(pA[mi]);

    for (int t = 0; t < NTT; ++t) {
        u16x8 anx[4];
        if (t + 1 < NTT) {
#pragma unroll
            for (int mi = 0; mi < 4; ++mi)
                anx[mi] = *(const u16x8*)(pA[mi] + (t + 1) * 512);
        }
        u16x8 b[4];
#pragma unroll
        for (int ni = 0; ni < 4; ++ni)
            b[ni] = *(const u16x8*)(pB[ni] + t * 512);
#pragma unroll
        for (int mi = 0; mi < 4; ++mi)
#pragma unroll
            for (int ni = 0; ni < 4; ++ni)
                acc[mi][ni] = __builtin_amdgcn_mfma_f32_16x16x32_bf16(
                    __builtin_bit_cast(bf16x8, acur[mi]),
                    __builtin_bit_cast(bf16x8, b[ni]),
                    acc[mi][ni], 0, 0, 0);
        if (t + 1 < NTT) {
#pragma unroll
            for (int mi = 0; mi < 4; ++mi) acur[mi] = anx[mi];
        }
    }

    // epilogue: C/D layout col=lane&15, row=quad*4+reg; add fp32 diagonal term
    const float h0 = filt[735];
    float gwv[4];
    int   ncol[4];
#pragma unroll
    for (int ni = 0; ni < 4; ++ni) {
        int ic   = blockIdx.y * 128 + (wn * 4 + ni) * 16 + l16;
        ncol[ni] = 2 * ic + p;
        gwv[ni]  = h0 * 0.05f * cosf(((float)ncol[ni] - 367.5f) * 0.001f);
    }
#pragma unroll
    for (int mi = 0; mi < 4; ++mi) {
#pragma unroll
        for (int ni = 0; ni < 4; ++ni) {
            if (ncol[ni] < DET) {
#pragma unroll
                for (int r = 0; r < 4; ++r) {
                    size_t rowg = (size_t)(rblk0 + mi) * 16 + quad * 4 + r;
                    float xd = sino[rowg * DET + ncol[ni]];
                    C[rowg * DET + ncol[ni]] = acc[mi][ni][r] + gwv[ni] * xd;
                }
            }
        }
    }
}

extern "C" void kernel_launch(void* const* d_in, const int* in_sizes, int n_in,
                              void* d_out, int out_size, void* d_ws, size_t ws_size,
                              hipStream_t stream) {
    const float* sino = (const float*)d_in[0];
    const float* filt = (const float*)d_in[1];
    (void)in_sizes; (void)n_in; (void)out_size; (void)ws_size;

    const size_t ASZ = (size_t)NRB * CPB2 * 8;   // elems per A' array (7,077,888)
    const size_t BSZ = (size_t)24 * CPB2 * 8;    // elems per B' array (147,456)

    ushort_t* Ae = (ushort_t*)d_ws;
    ushort_t* Ao = Ae + ASZ;
    ushort_t* Be = Ao + ASZ;
    ushort_t* Bo = Be + BSZ;
    float* out = (float*)d_out;

    prep_af<<<(NRB * CPB2) / 256, 256, 0, stream>>>(sino, Ae, Ao);
    prep_bf<<<(24 * CPB2) / 256, 256, 0, stream>>>(filt, Be, Bo);

    dim3 grid(NRB / 32, 3, 2);   // 36 x 3 x 2 = 216 blocks
    gemm_half<<<grid, 1024, 0, stream>>>(Ae, Ao, Be, Bo, sino, filt, out);
}

// Round 8
// 153.004 us; speedup vs baseline: 1.0378x; 1.0378x over previous
//
#include <hip/hip_runtime.h>

typedef unsigned short ushort_t;
typedef ushort_t u16x4 __attribute__((ext_vector_type(4)));
typedef ushort_t u16x8 __attribute__((ext_vector_type(8)));
typedef __bf16 bf16x8 __attribute__((ext_vector_type(8)));
typedef float f32x4 __attribute__((ext_vector_type(4)));

#define DET 736
#define HALF 368           // real half-K (odd or even samples)
#define NTT 12             // K-tiles of 32 (padded K = 384)
#define CPB2 (NTT * 64)    // 768 frag-chunks per 16-col block of B'
#define RB 64              // sinogram rows per block
#define LDR 392            // padded LDS half-row stride (elems): 784 B = 4 banks offset/row
#define APAR (RB * LDR)    // 25088 elems per parity plane

// ---------------------------------------------------------------------------
// PARITY SPLIT (round-7-verified algebra), A-STATIONARY FUSED (this round):
//   OUT[m][2i]   = sum_j x[m][2j+1] Be[i][j]  +  h0 g(2i)   x[m][2i]
//   OUT[m][2i+1] = sum_j x[m][2j]   Bo[i][j]  +  h0 g(2i+1) x[m][2i+1]
// Block stages its 64 rows (both parities, bf16) into LDS once; K-loop is
// barrier-free: A frags ds_read (2-way bank = free), B' frags global->reg
// (frag-major contiguous, 0.59 MB L2-resident). Both parities written by the
// same block -> interleaved column writes merge to full lines in one L2.
// Diagonal term re-reads sino fp32 (L2-hot: this block staged those rows).
// ---------------------------------------------------------------------------

// Be[i][j] = g(2j+1) h[2(j-i)+1]  (even outputs);  Bo[i][j] = g(2j) h[2(j-i)-1].
// Frag-major: chunk (cb,t,lane): i = cb*16+(lane&15), j = t*32+(lane>>4)*8+e.
__global__ void prep_bf(const float* __restrict__ filt,
                        ushort_t* __restrict__ Be, ushort_t* __restrict__ Bo) {
    int c = blockIdx.x * blockDim.x + threadIdx.x;   // exact: 24*CPB2 = 18432
    int cb  = c / CPB2;
    int rem = c - cb * CPB2;
    int t = rem >> 6, lane = rem & 63;
    int i = cb * 16 + (lane & 15);
    int quad = lane >> 4;
    u16x8 ve, vo;
#pragma unroll
    for (int e = 0; e < 8; ++e) {
        int j = t * 32 + quad * 8 + e;
        bool real = (j < HALF) && (i < HALF);
        int de = 2 * (j - i) + 1 + 735;                       // clamped indices
        int do_ = de - 2;
        de  = de  < 0 ? 0 : (de  > 1470 ? 1470 : de);
        do_ = do_ < 0 ? 0 : (do_ > 1470 ? 1470 : do_);
        float ge = 0.05f * cosf(((float)(2 * j + 1) - 367.5f) * 0.001f);
        float go = 0.05f * cosf(((float)(2 * j)     - 367.5f) * 0.001f);
        float fe = filt[de] * ge;
        float fo = filt[do_] * go;
        ve[e] = real ? __builtin_bit_cast(ushort_t, (__bf16)fe) : (ushort_t)0;
        vo[e] = real ? __builtin_bit_cast(ushort_t, (__bf16)fo) : (ushort_t)0;
    }
    *(u16x8*)(Be + (size_t)c * 8) = ve;
    *(u16x8*)(Bo + (size_t)c * 8) = vo;
}

// Block: 64 rows x all 768 padded output cols. 16 waves: wid>>3 = parity,
// (wid&7)*3 = col-block base; each wave = 4 row-blocks x 3 col-blocks.
__global__ __launch_bounds__(1024, 4) void gemm_fused(
    const float* __restrict__ sino,
    const ushort_t* __restrict__ Be, const ushort_t* __restrict__ Bo,
    const float* __restrict__ filt,
    float* __restrict__ C)
{
    __shared__ ushort_t As[2 * APAR];   // [parity][row][LDR] = 100,352 B

    const int tid  = threadIdx.x;
    const int lane = tid & 63;
    const int wid  = tid >> 6;          // 0..15
    const int quad = lane >> 4;
    const int l16  = lane & 15;

    const size_t row_a0 = (size_t)blockIdx.x * RB;

    // ---- stage 64 rows, parity-deinterleaved, fp32 -> bf16 (once) ----
    for (int c = tid; c < RB * 92; c += 1024) {      // 92 chunks of 8 f32 per row
        int row = c / 92;
        int cp  = c - row * 92;
        const float* g = sino + (row_a0 + row) * DET + cp * 8;
        f32x4 lo = *(const f32x4*)g;
        f32x4 hi = *(const f32x4*)(g + 4);
        // even cols (samples x[2j]) feed ODD outputs -> plane 1
        // odd  cols (samples x[2j+1]) feed EVEN outputs -> plane 0
        u16x4 vod, vev;
        vod[0] = __builtin_bit_cast(ushort_t, (__bf16)lo[1]);
        vod[1] = __builtin_bit_cast(ushort_t, (__bf16)lo[3]);
        vod[2] = __builtin_bit_cast(ushort_t, (__bf16)hi[1]);
        vod[3] = __builtin_bit_cast(ushort_t, (__bf16)hi[3]);
        vev[0] = __builtin_bit_cast(ushort_t, (__bf16)lo[0]);
        vev[1] = __builtin_bit_cast(ushort_t, (__bf16)lo[2]);
        vev[2] = __builtin_bit_cast(ushort_t, (__bf16)hi[0]);
        vev[3] = __builtin_bit_cast(ushort_t, (__bf16)hi[2]);
        *(u16x4*)(As + row * LDR + cp * 4)        = vod;   // plane 0: odd samples
        *(u16x4*)(As + APAR + row * LDR + cp * 4) = vev;   // plane 1: even samples
    }
    // zero K-pad j = 368..383 (MFMA reads it; avoid NaN*0)
    if (tid < 128) {
        int p = tid & 1, row = tid >> 1;
        ushort_t* z = As + p * APAR + row * LDR + HALF;
        *(u16x8*)(z)     = (u16x8){0,0,0,0,0,0,0,0};
        *(u16x8*)(z + 8) = (u16x8){0,0,0,0,0,0,0,0};
    }
    __syncthreads();   // the only barrier

    // ---- barrier-free K-loop ----
    const int p    = wid >> 3;            // 0: even outputs, 1: odd
    const int cb0  = (wid & 7) * 3;       // 3 col-blocks of 16 half-cols
    const ushort_t* Bfp = p ? Bo : Be;

    f32x4 acc[4][3];
#pragma unroll
    for (int i = 0; i < 4; ++i)
#pragma unroll
        for (int j = 0; j < 3; ++j)
            acc[i][j] = (f32x4){0.f, 0.f, 0.f, 0.f};

    int aoff[4];
#pragma unroll
    for (int mi = 0; mi < 4; ++mi)
        aoff[mi] = p * APAR + (mi * 16 + l16) * LDR + quad * 8;

    const ushort_t* pB[3];
#pragma unroll
    for (int ni = 0; ni < 3; ++ni)
        pB[ni] = Bfp + ((size_t)(cb0 + ni) * CPB2 + lane) * 8;

    u16x8 bcur[3];
#pragma unroll
    for (int ni = 0; ni < 3; ++ni)
        bcur[ni] = *(const u16x8*)(pB[ni]);

    for (int t = 0; t < NTT; ++t) {
        u16x8 bnx[3];
        if (t + 1 < NTT) {
#pragma unroll
            for (int ni = 0; ni < 3; ++ni)
                bnx[ni] = *(const u16x8*)(pB[ni] + (t + 1) * 512);
        }
        u16x8 a[4];
#pragma unroll
        for (int mi = 0; mi < 4; ++mi)
            a[mi] = *(const u16x8*)(As + aoff[mi] + t * 32);
#pragma unroll
        for (int mi = 0; mi < 4; ++mi)
#pragma unroll
            for (int ni = 0; ni < 3; ++ni)
                acc[mi][ni] = __builtin_amdgcn_mfma_f32_16x16x32_bf16(
                    __builtin_bit_cast(bf16x8, a[mi]),
                    __builtin_bit_cast(bf16x8, bcur[ni]),
                    acc[mi][ni], 0, 0, 0);
        if (t + 1 < NTT) {
#pragma unroll
            for (int ni = 0; ni < 3; ++ni) bcur[ni] = bnx[ni];
        }
    }

    // ---- epilogue: C/D col=lane&15, row=quad*4+reg; + fp32 diagonal term ----
    const float h0 = filt[735];
#pragma unroll
    for (int ni = 0; ni < 3; ++ni) {
        int ic   = (cb0 + ni) * 16 + l16;
        int colg = 2 * ic + p;
        if (colg < DET) {
            float gw = h0 * 0.05f * cosf(((float)colg - 367.5f) * 0.001f);
#pragma unroll
            for (int mi = 0; mi < 4; ++mi) {
#pragma unroll
                for (int r = 0; r < 4; ++r) {
                    size_t rowg = row_a0 + mi * 16 + quad * 4 + r;
                    float xd = sino[rowg * DET + colg];   // L2-hot (staged above)
                    C[rowg * DET + colg] = acc[mi][ni][r] + gw * xd;
                }
            }
        }
    }
}

extern "C" void kernel_launch(void* const* d_in, const int* in_sizes, int n_in,
                              void* d_out, int out_size, void* d_ws, size_t ws_size,
                              hipStream_t stream) {
    const float* sino = (const float*)d_in[0];
    const float* filt = (const float*)d_in[1];
    (void)in_sizes; (void)n_in; (void)out_size; (void)ws_size;

    const size_t BSZ = (size_t)24 * CPB2 * 8;    // 147,456 elems per B' array

    ushort_t* Be = (ushort_t*)d_ws;
    ushort_t* Bo = Be + BSZ;
    float* out = (float*)d_out;

    prep_bf<<<72, 256, 0, stream>>>(filt, Be, Bo);

    gemm_fused<<<dim3(288), 1024, 0, stream>>>(sino, Be, Bo, filt, out);
}

// Round 11
// 138.605 us; speedup vs baseline: 1.1457x; 1.1039x over previous
//
#include <hip/hip_runtime.h>

typedef unsigned short ushort_t;
typedef ushort_t u16x8 __attribute__((ext_vector_type(8)));
typedef __bf16 bf16x8 __attribute__((ext_vector_type(8)));
typedef float f32x4 __attribute__((ext_vector_type(4)));

#define DET 736
#define HALF 368           // real half-size (even or odd samples)
#define NTT 12             // K-tiles of 32 (padded K = 384)
#define CPB2 (NTT * 64)    // 768 frag-chunks per 16-row (or 16-col) block
#define NRB 1152           // M/16 row-blocks (M = 18432)

// ---------------------------------------------------------------------------
// PARITY SPLIT (verified rounds 7/8):
//   OUT[m][2i]   = sum_j x[m][2j+1] Be[i][j]  +  h0 g(2i)   x[m][2i]
//   OUT[m][2i+1] = sum_j x[m][2j]   Bo[i][j]  +  h0 g(2i+1) x[m][2i+1]
// Each wave computes BOTH parities for the SAME half-col block i, so lane l16
// holds adjacent output cols (2i, 2i+1) -> float2 stores are fully DENSE
// (rounds 7/8 showed stride-2 writes cost 2x WRITE + write-allocate FETCH).
// No LDS, no barriers: A' frags stream from L3 (28 MB x3 re-read), B'
// (0.59 MB) is L2-resident, frag-major so all loads are 16B/lane contiguous.
// Round-10 de-risk: dropped the (512,4) launch-bounds min-occupancy arg --
// it forced a 128-VGPR cap and guaranteed scratch spill (the only compile-
// level difference vs all prior passing rounds). Spill-free > 1 extra block.
// ---------------------------------------------------------------------------

// Ae = odd-k samples (feeds even outputs), Ao = even-k samples (feeds odd).
__global__ void prep_af(const float* __restrict__ sino,
                        ushort_t* __restrict__ Ae, ushort_t* __restrict__ Ao) {
    int c = blockIdx.x * blockDim.x + threadIdx.x;   // exact grid: NRB*CPB2
    int rblk = c / CPB2;
    int rem  = c - rblk * CPB2;
    int t = rem >> 6, lane = rem & 63;
    int rr = lane & 15, quad = lane >> 4;
    int j0 = t * 32 + quad * 8;        // first of 8 half-K indices (mult of 8)
    u16x8 ve, vo;
    if (j0 < HALF) {                   // j0<=360 -> all 8 real
        const float* g = sino + (size_t)(rblk * 16 + rr) * DET + 2 * j0;
        float w[16];
        *(f32x4*)(w)      = *(const f32x4*)(g);
        *(f32x4*)(w + 4)  = *(const f32x4*)(g + 4);
        *(f32x4*)(w + 8)  = *(const f32x4*)(g + 8);
        *(f32x4*)(w + 12) = *(const f32x4*)(g + 12);
#pragma unroll
        for (int e = 0; e < 8; ++e) {
            vo[e] = __builtin_bit_cast(ushort_t, (__bf16)w[2 * e]);      // k even
            ve[e] = __builtin_bit_cast(ushort_t, (__bf16)w[2 * e + 1]);  // k odd
        }
    } else {
#pragma unroll
        for (int e = 0; e < 8; ++e) { ve[e] = 0; vo[e] = 0; }
    }
    *(u16x8*)(Ae + (size_t)c * 8) = ve;
    *(u16x8*)(Ao + (size_t)c * 8) = vo;
}

// Be[i][j] = g(2j+1) h[2(j-i)+1]  (even outputs);  Bo[i][j] = g(2j) h[2(j-i)-1].
// Frag-major: chunk (cb,t,lane): i = cb*16+(lane&15), j = t*32+(lane>>4)*8+e.
__global__ void prep_bf(const float* __restrict__ filt,
                        ushort_t* __restrict__ Be, ushort_t* __restrict__ Bo) {
    int c = blockIdx.x * blockDim.x + threadIdx.x;   // exact: 24*CPB2 = 18432
    int cb  = c / CPB2;
    int rem = c - cb * CPB2;
    int t = rem >> 6, lane = rem & 63;
    int i = cb * 16 + (lane & 15);
    int quad = lane >> 4;
    u16x8 ve, vo;
#pragma unroll
    for (int e = 0; e < 8; ++e) {
        int j = t * 32 + quad * 8 + e;
        bool real = (j < HALF) && (i < HALF);
        int de = 2 * (j - i) + 1 + 735;                       // clamped indices
        int do_ = de - 2;
        de  = de  < 0 ? 0 : (de  > 1470 ? 1470 : de);
        do_ = do_ < 0 ? 0 : (do_ > 1470 ? 1470 : do_);
        float ge = 0.05f * cosf(((float)(2 * j + 1) - 367.5f) * 0.001f);
        float go = 0.05f * cosf(((float)(2 * j)     - 367.5f) * 0.001f);
        float fe = filt[de] * ge;
        float fo = filt[do_] * go;
        ve[e] = real ? __builtin_bit_cast(ushort_t, (__bf16)fe) : (ushort_t)0;
        vo[e] = real ? __builtin_bit_cast(ushort_t, (__bf16)fo) : (ushort_t)0;
    }
    *(u16x8*)(Be + (size_t)c * 8) = ve;
    *(u16x8*)(Bo + (size_t)c * 8) = vo;
}

// Block = 512 thr = 8 waves (4M x 2N): 128 rows x 256 full cols.
// Wave = 2 row-blocks x 4 half-col blocks x BOTH parities.
// Grid (144, 3) = 432 blocks. No LDS, no barriers.
__global__ __launch_bounds__(512) void gemm_pair(
    const ushort_t* __restrict__ Ae, const ushort_t* __restrict__ Ao,
    const ushort_t* __restrict__ Be, const ushort_t* __restrict__ Bo,
    const float* __restrict__ sino, const float* __restrict__ filt,
    float* __restrict__ C)
{
    const int tid  = threadIdx.x;
    const int lane = tid & 63;
    const int wid  = tid >> 6;     // 0..7
    const int wm   = wid >> 1;     // 0..3
    const int wn   = wid & 1;      // 0..1
    const int quad = lane >> 4;
    const int l16  = lane & 15;

    const int rblk0 = blockIdx.x * 8 + wm * 2;   // 2 row-blocks (32 rows)
    const int cb0   = blockIdx.y * 8 + wn * 4;   // 4 half-col blocks

    f32x4 acc_e[2][4], acc_o[2][4];
#pragma unroll
    for (int mi = 0; mi < 2; ++mi)
#pragma unroll
        for (int ni = 0; ni < 4; ++ni) {
            acc_e[mi][ni] = (f32x4){0.f, 0.f, 0.f, 0.f};
            acc_o[mi][ni] = (f32x4){0.f, 0.f, 0.f, 0.f};
        }

    const ushort_t* pAe[2]; const ushort_t* pAo[2];
#pragma unroll
    for (int mi = 0; mi < 2; ++mi) {
        size_t off = ((size_t)(rblk0 + mi) * CPB2 + lane) * 8;
        pAe[mi] = Ae + off;
        pAo[mi] = Ao + off;
    }
    const ushort_t* pBe[4]; const ushort_t* pBo[4];
#pragma unroll
    for (int ni = 0; ni < 4; ++ni) {
        size_t off = ((size_t)(cb0 + ni) * CPB2 + lane) * 8;
        pBe[ni] = Be + off;
        pBo[ni] = Bo + off;
    }

#pragma unroll 2
    for (int t = 0; t < NTT; ++t) {
        const int off = t * 512;
        u16x8 ae[2], ao[2], be[4], bo[4];
#pragma unroll
        for (int mi = 0; mi < 2; ++mi) {
            ae[mi] = *(const u16x8*)(pAe[mi] + off);
            ao[mi] = *(const u16x8*)(pAo[mi] + off);
        }
#pragma unroll
        for (int ni = 0; ni < 4; ++ni) {
            be[ni] = *(const u16x8*)(pBe[ni] + off);
            bo[ni] = *(const u16x8*)(pBo[ni] + off);
        }
#pragma unroll
        for (int mi = 0; mi < 2; ++mi)
#pragma unroll
            for (int ni = 0; ni < 4; ++ni) {
                acc_e[mi][ni] = __builtin_amdgcn_mfma_f32_16x16x32_bf16(
                    __builtin_bit_cast(bf16x8, ae[mi]),
                    __builtin_bit_cast(bf16x8, be[ni]),
                    acc_e[mi][ni], 0, 0, 0);
                acc_o[mi][ni] = __builtin_amdgcn_mfma_f32_16x16x32_bf16(
                    __builtin_bit_cast(bf16x8, ao[mi]),
                    __builtin_bit_cast(bf16x8, bo[ni]),
                    acc_o[mi][ni], 0, 0, 0);
            }
    }

    // epilogue: lane l16 holds cols (2*ic, 2*ic+1) -> DENSE float2 stores.
    const float h0 = filt[735];
#pragma unroll
    for (int ni = 0; ni < 4; ++ni) {
        const int ic = (cb0 + ni) * 16 + l16;
        if (ic < HALF) {
            const float gw_e = h0 * 0.05f * cosf(((float)(2 * ic)     - 367.5f) * 0.001f);
            const float gw_o = h0 * 0.05f * cosf(((float)(2 * ic + 1) - 367.5f) * 0.001f);
#pragma unroll
            for (int mi = 0; mi < 2; ++mi) {
#pragma unroll
                for (int r = 0; r < 4; ++r) {
                    const size_t rowg = (size_t)(rblk0 + mi) * 16 + quad * 4 + r;
                    const float2 xd = *(const float2*)(sino + rowg * DET + 2 * ic);
                    float2 o;
                    o.x = acc_e[mi][ni][r] + gw_e * xd.x;
                    o.y = acc_o[mi][ni][r] + gw_o * xd.y;
                    *(float2*)(C + rowg * DET + 2 * ic) = o;
                }
            }
        }
    }
}

extern "C" void kernel_launch(void* const* d_in, const int* in_sizes, int n_in,
                              void* d_out, int out_size, void* d_ws, size_t ws_size,
                              hipStream_t stream) {
    const float* sino = (const float*)d_in[0];
    const float* filt = (const float*)d_in[1];
    (void)in_sizes; (void)n_in; (void)out_size; (void)ws_size;

    const size_t ASZ = (size_t)NRB * CPB2 * 8;   // 7,077,888 elems per A' array
    const size_t BSZ = (size_t)24 * CPB2 * 8;    // 147,456 elems per B' array

    ushort_t* Ae = (ushort_t*)d_ws;
    ushort_t* Ao = Ae + ASZ;
    ushort_t* Be = Ao + ASZ;
    ushort_t* Bo = Be + BSZ;
    float* out = (float*)d_out;

    prep_af<<<(NRB * CPB2) / 256, 256, 0, stream>>>(sino, Ae, Ao);
    prep_bf<<<(24 * CPB2) / 256, 256, 0, stream>>>(filt, Be, Bo);

    dim3 grid(NRB / 8, 3);   // 144 x 3 = 432 blocks
    gemm_pair<<<grid, 512, 0, stream>>>(Ae, Ao, Be, Bo, sino, filt, out);
}